// Round 15
// baseline (634.982 us; speedup 1.0000x reference)
//
#include <hip/hip_runtime.h>

// ---------------------------------------------------------------------------
// Problem constants
// ---------------------------------------------------------------------------
constexpr int CT = 32;      // T
constexpr int CN = 64;      // N
constexpr int CE = 256;     // E = DOBS*V
constexpr int CHID = 1024;
constexpr int CA = 32;      // num options
constexpr int CS = 32;      // planning steps
constexpr int CHP = 8;      // planning horizon
constexpr int TN = CT * CN; // 2048

// d_out float offsets (return order: search_logits, planned_actions, X, value,
// model_loss, embed_loss)
constexpr size_t O_SL  = 0;        // 32*64*32 = 65536
constexpr size_t O_PA  = 65536;    // 64*8     = 512
constexpr size_t O_X   = 66048;    // 64*8*256 = 131072
constexpr size_t O_VAL = 197120;   // 32*64    = 2048
constexpr size_t O_ML  = 199168;   // 32*64*256= 524288
constexpr size_t O_EL  = 723456;   // 32*64    = 2048

// ws byte offsets (~100 MB total)
constexpr size_t B_EMB    = 0;                           // 2 MB   [2048][256] f32
constexpr size_t B_H1     = 2u * 1024 * 1024;            // 256 KB [64][1024]
// control block at 3.5 MB (nothing else lives in 3.5..4 MB)
constexpr size_t B_FLG    = 3584u * 1024;                // 64*8*16 ints = 32 KB
constexpr size_t B_CNTTL  = B_FLG + 64 * 1024;           // 32 ints
constexpr size_t B_LISTTL = B_CNTTL + 4 * 1024;          // 32 KB [32][256]
// 32MB+ multi-phase region: We2T (early) -> Wm1T (mid) -> xstl/parttl/Wm2T
constexpr size_t B_R32    = 4u * 1024 * 1024;
constexpr size_t B_WE2T   = B_R32;                       // 1 MB  (dead after x0)
constexpr size_t B_WM1T   = B_R32;                       // 32 MB (dead after wpm)
constexpr size_t B_XSTL   = B_R32;                       // 4 MB  [2048][512]
constexpr size_t B_PARTTL = B_R32 + 12u * 1024 * 1024;   // 16 MB [2048][8][256]
// plan part buffer: PER-STEP slots (33 x 64 x 8 x 256 f32 = 16.5 MB) at +4MB
// abs, overlapping only xstl/parttl -- dead after ml_kernel (stream-ordered
// before plan2). Slots never reused -> no overwrite race, ever.
constexpr size_t B_PART3  = B_R32;                       // 16.5 MB [33][64][8][256]
constexpr size_t B_WM2T   = B_R32 + 28u * 1024 * 1024;   // 1 MB  [1024][256] (abs +32MB)
constexpr size_t B_WPM    = B_R32 + 32u * 1024 * 1024;   // 64 MB [32][512][1024]

// LDS scalar-state indices
constexpr int SI_FLAG = 0, SI_I = 1, SI_PUSH = 2, SI_IUP = 3;

__device__ __forceinline__ void fma4(float4& a, float s, const float4& w) {
  a.x = fmaf(s, w.x, a.x); a.y = fmaf(s, w.y, a.y);
  a.z = fmaf(s, w.z, a.z); a.w = fmaf(s, w.w, a.w);
}

// LLC-coherent relaxed accessors (cross-block data; no fences needed: producer
// ordering via __syncthreads' vmcnt drain + explicit waitst before flag post)
__device__ __forceinline__ float gld(const float* p) {
  return __hip_atomic_load(p, __ATOMIC_RELAXED, __HIP_MEMORY_SCOPE_AGENT);
}
__device__ __forceinline__ void gst(float* p, float v) {
  __hip_atomic_store(p, v, __ATOMIC_RELAXED, __HIP_MEMORY_SCOPE_AGENT);
}
__device__ __forceinline__ int gldi(const int* p) {
  return __hip_atomic_load(p, __ATOMIC_RELAXED, __HIP_MEMORY_SCOPE_AGENT);
}
__device__ __forceinline__ void gsti(int* p, int v) {
  __hip_atomic_store(p, v, __ATOMIC_RELAXED, __HIP_MEMORY_SCOPE_AGENT);
}
__device__ __forceinline__ void waitst() {
  asm volatile("s_waitcnt vmcnt(0)" ::: "memory");
}
// LDS-only barrier: drains lgkmcnt (LDS ops) but leaves global loads in
// flight across the barrier (unlike __syncthreads' implicit vmcnt(0) drain).
// sched_barrier(0) pins code motion across the point (guide rule #18).
__device__ __forceinline__ void syncL() {
  asm volatile("s_waitcnt lgkmcnt(0)" ::: "memory");
  __builtin_amdgcn_s_barrier();
  __builtin_amdgcn_sched_barrier(0);
}

// ---------------------------------------------------------------------------
// init: zero PA+X span of d_out, per-chain flags, time-loop counters
// ---------------------------------------------------------------------------
__global__ void init_kernel(float* __restrict__ out, int* __restrict__ flg,
                            int* __restrict__ cnt_tl) {
  int idx = blockIdx.x * 256 + threadIdx.x;
  if (idx < 131584) out[O_PA + idx] = 0.f;  // PA (512) + X (131072) contiguous
  if (idx < CN * 8 * 16) flg[idx] = 0;
  if (idx < CA) cnt_tl[idx] = 0;
}

// ---------------------------------------------------------------------------
// emb[t][n][e] = embed1[obs[t][n][e>>4]][e&15]
// ---------------------------------------------------------------------------
__global__ void emb_kernel(const int* __restrict__ obs, const float* __restrict__ embed1,
                           float* __restrict__ emb) {
  int idx = blockIdx.x * 256 + threadIdx.x;
  int b = idx >> 5, k8 = idx & 31;
  int e0 = k8 * 8;
  int d = e0 >> 4;
  int o = obs[b * 16 + d];
  const float* src = embed1 + o * 16 + (e0 & 15);
  float4 v0 = *(const float4*)src;
  float4 v1 = *(const float4*)(src + 4);
  float* dst = emb + (size_t)b * CE + e0;
  *(float4*)dst = v0;
  *(float4*)(dst + 4) = v1;
}

// ---------------------------------------------------------------------------
// One GRU step with h0 = 0 (only Hs[0] used downstream; Whh provably unused)
// ---------------------------------------------------------------------------
__global__ void h1_kernel(const float* __restrict__ emb, const float* __restrict__ Wih,
                          const float* __restrict__ bih, const float* __restrict__ bhh,
                          float* __restrict__ h1) {
  int t = threadIdx.x, bid = blockIdx.x;   // 256 blocks of (64n x 4j)
  int n = t & 63, j = bid * 4 + (t >> 6);
  const float* x = emb + (size_t)n * CE;   // emb[0] rows
  const float* wr = Wih + (size_t)j * CE;
  const float* wz = Wih + (size_t)(CHID + j) * CE;
  const float* wn = Wih + (size_t)(2 * CHID + j) * CE;
  float ar = 0.f, az = 0.f, an = 0.f;
  #pragma unroll 4
  for (int e = 0; e < CE; ++e) {
    float xe = x[e];
    ar += xe * wr[e]; az += xe * wz[e]; an += xe * wn[e];
  }
  ar += bih[j] + bhh[j];
  az += bih[CHID + j] + bhh[CHID + j];
  float r = 1.f / (1.f + expf(-ar));
  float z = 1.f / (1.f + expf(-az));
  float nn = tanhf(an + bih[2 * CHID + j] + r * bhh[2 * CHID + j]);
  h1[(size_t)n * CHID + j] = (1.f - z) * nn;
}

// ---------------------------------------------------------------------------
// Generic 64x64 tiled transpose: in[R][C] -> out[C][R]
// ---------------------------------------------------------------------------
__global__ void trans_kernel(const float* __restrict__ in, float* __restrict__ out,
                             int R, int C) {
  __shared__ float tile[64][65];
  int tj = threadIdx.x & 63, tg = threadIdx.x >> 6;
  int cb = blockIdx.x * 64, rb = blockIdx.y * 64;
  #pragma unroll
  for (int i = 0; i < 16; ++i) {
    int r = tg * 16 + i;
    tile[r][tj] = in[(size_t)(rb + r) * C + cb + tj];
  }
  __syncthreads();
  #pragma unroll
  for (int i = 0; i < 16; ++i) {
    int c2 = tg * 16 + i;
    out[(size_t)(cb + c2) * R + rb + tj] = tile[tj][c2];
  }
}

// ---------------------------------------------------------------------------
// X[:,0] = h1 @ We2^T + be2   (We2T layout [k][e])
// ---------------------------------------------------------------------------
__global__ void x0_kernel(const float* __restrict__ h1, const float* __restrict__ We2T,
                          const float* __restrict__ be2, float* __restrict__ Xout) {
  int et = blockIdx.x, n = blockIdx.y, t = threadIdx.x;
  int el = t & 63, kq = t >> 6;
  __shared__ float hr[1024];
  __shared__ float sred2[4][64];
  for (int idx = t; idx < 1024; idx += 256) hr[idx] = h1[(size_t)n * CHID + idx];
  __syncthreads();
  int e = et * 64 + el;
  float acc = 0.f;
  for (int k = kq * 256; k < kq * 256 + 256; ++k) acc += hr[k] * We2T[(size_t)k * CE + e];
  sred2[kq][el] = acc;
  __syncthreads();
  if (t < 64) {
    float s2 = sred2[0][t] + sred2[1][t] + sred2[2][t] + sred2[3][t] + be2[et * 64 + t];
    Xout[(size_t)(n * CHP) * CE + et * 64 + t] = s2;
  }
}

// ---------------------------------------------------------------------------
// Factorized model weights:
// Wpm[o][e][j]     = sum_a relu( embed_opt[o][a]) * Wm1[j][a*256+e]
// Wpm[o][256+e][j] = sum_a relu(-embed_opt[o][a]) * Wm1[j][a*256+e]
// ---------------------------------------------------------------------------
__global__ void wpm_kernel(const float* __restrict__ Wm1T, const float* __restrict__ eo,
                           float* __restrict__ Wpm) {
  int e = blockIdx.x, jt = blockIdx.y, t = threadIdx.x;
  int j = jt * 256 + t;
  __shared__ float rp[CA * CA], rm[CA * CA];
  for (int idx = t; idx < CA * CA; idx += 256) {
    float v = eo[idx];
    rp[idx] = fmaxf(v, 0.f);
    rm[idx] = fmaxf(-v, 0.f);
  }
  __syncthreads();
  float w[32];
  #pragma unroll
  for (int a = 0; a < 32; ++a) w[a] = Wm1T[(size_t)(a * 256 + e) * CHID + j];
  for (int o = 0; o < 32; ++o) {
    float sp = 0.f, sm = 0.f;
    #pragma unroll
    for (int a = 0; a < 32; ++a) {
      float wa = w[a];
      sp += rp[o * 32 + a] * wa;
      sm += rm[o * 32 + a] * wa;
    }
    Wpm[((size_t)o * 512 + e) * CHID + j] = sp;
    Wpm[((size_t)o * 512 + 256 + e) * CHID + j] = sm;
  }
}

// ---------------------------------------------------------------------------
// Group time-loop rows by option (list order nondeterministic; results aren't)
// ---------------------------------------------------------------------------
__global__ void tllists_kernel(const int* __restrict__ P, int* __restrict__ cnt_tl,
                               int* __restrict__ list_tl) {
  int b = blockIdx.x * 256 + threadIdx.x;
  if (b >= TN) return;
  int a = P[b];
  int slot = atomicAdd(&cnt_tl[a], 1);
  list_tl[a * 256 + slot] = b;
}

// xs_tl[b][k] = relu(+/- prev[b][k&255]),  prev = emb shifted by one t (wrap)
__global__ void xstl_kernel(const float* __restrict__ emb, float* __restrict__ xs) {
  int idx = blockIdx.x * 256 + threadIdx.x;   // < 2048*512
  int b = idx >> 9, k = idx & 511;
  int e = k & 255;
  int bp = (b < CN) ? (b + (CT - 1) * CN) : (b - CN);
  float v = emb[(size_t)bp * CE + e];
  xs[idx] = (k < 256) ? fmaxf(v, 0.f) : fmaxf(-v, 0.f);
}

// ---------------------------------------------------------------------------
// Time-loop model, l1+l2 MERGED (replaces l1_kernel + l2big):
// h eighth stays in LDS, l2 eighth -> part[row][jt][e] directly.
// grid (32 o, 8 jt, 8 z), 256 thr.
// ---------------------------------------------------------------------------
__global__ __launch_bounds__(256) void tl_kernel(
    const float* __restrict__ Wpm, const float* __restrict__ xs,
    const float* __restrict__ bm1, const float* __restrict__ Wm2T,
    const int* __restrict__ cnt, const int* __restrict__ list,
    int listStride, float* __restrict__ part) {
  int o = blockIdx.x, jt = blockIdx.y;
  int c = cnt[o];
  if (c <= 0) return;
  __shared__ __align__(16) float sbuf[8192];
  __shared__ __align__(16) float hh[8 * 128];
  __shared__ int srows[8];
  int t = threadIdx.x;
  int jl = t & 31, kq = t >> 5;
  int jb = jt * 128;
  const float* wb = Wpm + (size_t)o * (512 * CHID) + jb + jl * 4;
  for (int g = blockIdx.z; g * 8 < c; g += gridDim.z) {
    int base = g * 8;
    int nr = min(8, c - base);
    if (t < 8) srows[t] = (t < nr) ? list[o * listStride + base + t] : -1;
    __syncthreads();
    for (int idx = t; idx < 4096; idx += 256) {
      int row = srows[idx >> 9];
      sbuf[idx] = (row >= 0) ? xs[(size_t)row * 512 + (idx & 511)] : 0.f;
    }
    __syncthreads();
    float4 acc[8];
    #pragma unroll
    for (int r = 0; r < 8; ++r) acc[r] = make_float4(0.f, 0.f, 0.f, 0.f);
    int kbase = kq * 64;
    for (int k4 = 0; k4 < 64; k4 += 4) {
      int k = kbase + k4;
      float4 w0 = *(const float4*)(wb + (size_t)(k + 0) * CHID);
      float4 w1 = *(const float4*)(wb + (size_t)(k + 1) * CHID);
      float4 w2 = *(const float4*)(wb + (size_t)(k + 2) * CHID);
      float4 w3 = *(const float4*)(wb + (size_t)(k + 3) * CHID);
      #pragma unroll
      for (int r = 0; r < 8; ++r) {
        float4 xv = *(const float4*)&sbuf[r * 512 + k];
        fma4(acc[r], xv.x, w0); fma4(acc[r], xv.y, w1);
        fma4(acc[r], xv.z, w2); fma4(acc[r], xv.w, w3);
      }
    }
    __syncthreads();
    #pragma unroll
    for (int r = 0; r < 8; ++r)
      *(float4*)&sbuf[(kq * 8 + r) * 128 + jl * 4] = acc[r];
    __syncthreads();
    for (int idx = t; idx < 1024; idx += 256) {
      int r = idx >> 7, jc = idx & 127;
      float ssum = 0.f;
      #pragma unroll
      for (int q8 = 0; q8 < 8; ++q8) ssum += sbuf[(q8 * 8 + r) * 128 + jc];
      hh[r * 128 + jc] = fmaxf(ssum + bm1[jb + jc], 0.f);
    }
    __syncthreads();
    // l2 eighth: thread t = e; part[row][jt][e] = sum_j hh[r][j]*Wm2T[jb+j][e]
    float acc2[8];
    #pragma unroll
    for (int r = 0; r < 8; ++r) acc2[r] = 0.f;
    for (int jj = 0; jj < 128; jj += 4) {
      float w0 = Wm2T[(size_t)(jb + jj + 0) * CE + t];
      float w1 = Wm2T[(size_t)(jb + jj + 1) * CE + t];
      float w2 = Wm2T[(size_t)(jb + jj + 2) * CE + t];
      float w3 = Wm2T[(size_t)(jb + jj + 3) * CE + t];
      #pragma unroll
      for (int r = 0; r < 8; ++r) {
        float4 hv = *(const float4*)&hh[r * 128 + jj];
        acc2[r] += hv.x * w0 + hv.y * w1 + hv.z * w2 + hv.w * w3;
      }
    }
    #pragma unroll
    for (int r = 0; r < 8; ++r)
      if (srows[r] >= 0)
        part[((size_t)srows[r] * 8 + jt) * CE + t] = acc2[r];
    __syncthreads();
  }
}

// model_loss = (sum(partials)+bm2 - emb)^2
__global__ void ml_kernel(const float* __restrict__ part, const float* __restrict__ bm2,
                          const float* __restrict__ emb, float* __restrict__ ML) {
  int idx = blockIdx.x * 256 + threadIdx.x;   // < 2048*256
  int b = idx >> 8, e = idx & 255;
  float outv = bm2[e];
  #pragma unroll
  for (int q = 0; q < 8; ++q) outv += part[((size_t)b * 8 + q) * CE + e];
  float d = outv - emb[idx];
  ML[idx] = d * d;
}

// ---------------------------------------------------------------------------
// plan2: 512 blocks = 64 independent chains x 8 j-eighth blocks, 512 thr.
// Round-15 changes (protocol from round 14 is UNTOUCHED -- unconditional
// flag post after full __syncthreads, per-step part slots):
//  (1) syncL (lgkm-only barrier) for all LDS-only coordination: no vmcnt(0)
//      drain stall, and global loads survive across barriers.
//  (2) SPECULATIVE W prefetch: a = P[s][n] is an input; gather rows depend
//      only on sign(x). Issue all 16 float4 W loads right after the epilogue;
//      the decision runs under the fetch; FMA waits at use inside PUSH.
//  (3) epilogue: every thread spins on all 8 flags itself (no barrier).
//  (4) decision: shuffle-reduced, is_new via wave-0 __ballot; 2 syncL total.
// ---------------------------------------------------------------------------
__global__ __launch_bounds__(512) void plan2_kernel(
    const float* __restrict__ Wpm, const float* __restrict__ Wm2T,
    const float* __restrict__ bm1g, const int* __restrict__ P,
    const float* __restrict__ Wsg, const float* __restrict__ bsg,
    const float* __restrict__ Wcg, const float* __restrict__ bcg,
    const float* __restrict__ bm2, float* __restrict__ Xout,
    float* __restrict__ SLout, float* __restrict__ VALout,
    float* __restrict__ PAout, int* __restrict__ flg,
    float* __restrict__ part_db) {
  __shared__ float Xlds[CHP * CE];      // replicated plan buffer (8 KB)
  __shared__ float sh[128];             // h eighth
  __shared__ __align__(16) float red[2048];  // 16-way partials / l2 halves
  __shared__ float sx[256];
  __shared__ float sred[8];
  __shared__ float svals[32];
  __shared__ int   sint[4];
  __shared__ float logits_s[32];

  int bid = blockIdx.x, t = threadIdx.x;
  int n = bid >> 3, q = bid & 7;
  int jb = q * 128;
  int c2 = t >> 3, g = t & 7;
  int jq = t & 31, kg = t >> 5;         // l1: jq = float4 j-lane, kg = row-group
  int e2 = t & 255, hf = t >> 8;        // l2: e lane, kl half

  // prologue: replicated chain state
  for (int idx = t; idx < CHP * CE; idx += 512)
    Xlds[idx] = Xout[(size_t)n * (CHP * CE) + idx];
  if (t < 32) logits_s[t] = 0.f;
  if (t < 4) sint[t] = 0;
  __syncthreads();

  for (int s = 0; s <= CS; ++s) {
    // read-only prefetch (L2-warm; hidden under the flag wait)
    float wsv = 0.f, bm2v = 0.f, bcv = 0.f, bsv = bsg[0];
    float wcv[32];
    if (t < 256) {
      wsv = Wsg[t]; bm2v = bm2[t];
      #pragma unroll
      for (int i = 0; i < 32; ++i) wcv[i] = Wcg[c2 * CE + g * 32 + i];
    }
    if (t < CA) bcv = bcg[t];

    // ---- epilogue of step s-1: every thread verifies all 8 producers ----
    if (s > 0) {
      #pragma unroll
      for (int f = 0; f < 8; ++f) {
        const int* fp = &flg[(n * 8 + f) * 16];
        while (gldi(fp) < s) __builtin_amdgcn_s_sleep(1);
      }
      if (sint[SI_PUSH]) {
        int Iup = sint[SI_IUP];
        if (t < 256) {
          float outv = bm2v;
          #pragma unroll
          for (int qq = 0; qq < 8; ++qq)
            outv += gld(&part_db[(((size_t)(s - 1) * CN + n) * 8 + qq) * CE + t]);
          Xlds[Iup * CE + t] = outv;
          if (q == 0) Xout[((size_t)(n * CHP) + Iup) * CE + t] = outv;
          sx[t] = outv;
        }
        if (t == 0) sint[SI_I] = Iup;
      } else {
        int I0 = sint[SI_I];
        int Inew = (I0 - 1 > 0) ? I0 - 1 : 0;
        if (t < 256) sx[t] = Xlds[Inew * CE + t];
        if (t == 0) sint[SI_I] = Inew;
      }
      if (s == CS) break;  // final epilogue only (uniform)
    } else {
      if (t < 256) sx[t] = Xlds[t];
      if (t == 0) sint[SI_I] = 0;
    }
    syncL();               // sx/sint visible (LDS only; loads may stay in flight)
    int I = sint[SI_I];
    int a = P[s * CN + n]; // static input: known BEFORE the decision

    // ---- SPECULATIVE W gather: issue 16 float4 loads now, use after decision
    const float* wbase = Wpm + (size_t)a * (512 * CHID) + jb + jq * 4;
    float4 wr[16];
    float  xa16[16];
    #pragma unroll
    for (int ii = 0; ii < 16; ++ii) {
      int e = kg * 16 + ii;
      float xv = sx[e];
      xa16[ii] = fabsf(xv);
      int row = (xv > 0.f) ? e : 256 + e;
      wr[ii] = *(const float4*)(wbase + (size_t)row * CHID);
    }

    // ---- decision segment A (runs under the W fetch) ----
    if (t < 256) {
      float v = fmaxf(sx[t], 0.f) * wsv;
      #pragma unroll
      for (int off = 32; off > 0; off >>= 1) v += __shfl_down(v, off, 64);
      if ((t & 63) == 0) sred[t >> 6] = v;
      float pv = 0.f;
      #pragma unroll 4
      for (int i = 0; i < 32; ++i)
        pv += fmaxf(sx[g * 32 + i], 0.f) * wcv[i];
      pv += __shfl_down(pv, 4, 8);
      pv += __shfl_down(pv, 2, 8);
      pv += __shfl_down(pv, 1, 8);
      if (g == 0) svals[c2] = pv + bcv;
    }
    syncL();
    // ---- decision segment B (wave 0 only; is_new via ballot) ----
    if (t < CA) {
      float sharp = sred[0] + sred[1] + sred[2] + sred[3] + bsv;
      bool nz = (logits_s[t] != 0.f);
      unsigned long long bal = __ballot(nz);
      float v = svals[t];
      float slv = (bal == 0ull) ? sharp * v : logits_s[t];
      if (q == 0) SLout[(size_t)(s * CN + n) * CA + t] = slv;
      logits_s[t] = slv - (t == a ? 1e8f : 0.f);
      if (t == a) {
        if (q == 0) { VALout[s * CN + n] = slv; PAout[n * CHP + I] = (float)a; }
        sint[SI_PUSH] = (v > 0.f) ? 1 : 0;
        sint[SI_IUP] = (I + 1 < CHP - 1) ? I + 1 : CHP - 1;
      }
    }
    syncL();

    // ---- model eval (push only): prefetched W, compacted 256-row stream ----
    if (sint[SI_PUSH]) {
      float4 acc; acc.x = acc.y = acc.z = acc.w = 0.f;
      #pragma unroll
      for (int ii = 0; ii < 16; ++ii) fma4(acc, xa16[ii], wr[ii]);
      *(float4*)&red[kg * 128 + jq * 4] = acc;
      syncL();
      if (t < 128) {
        float s1 = 0.f;
        #pragma unroll
        for (int gg = 0; gg < 16; ++gg) s1 += red[gg * 128 + t];
        sh[t] = fmaxf(s1 + bm1g[jb + t], 0.f);
      }
      syncL();
      // l2: part_q[e] = sum_{kl<128} sh[kl] * Wm2T[(jb+kl)*CE+e], 2x64 split
      {
        const float* w2 = Wm2T + (size_t)(jb + hf * 64) * CE + e2;
        float a2 = 0.f;
        #pragma unroll 8
        for (int kl = 0; kl < 64; ++kl)
          a2 = fmaf(sh[hf * 64 + kl], w2[(size_t)kl * CE], a2);
        red[hf * 256 + e2] = a2;
      }
      syncL();
      if (t < 256) {
        gst(&part_db[(((size_t)s * CN + n) * 8 + q) * CE + t],
            red[t] + red[256 + t]);
      }
    }
    __syncthreads();              // full drain: all threads' part stores done
    if (t == 0) {
      waitst();
      gsti(&flg[(n * 8 + q) * 16], s + 1);   // UNCONDITIONAL post
    }
    __syncthreads();
  }
}

// ---------------------------------------------------------------------------
// embed_loss
// ---------------------------------------------------------------------------
__global__ void el_kernel(const float* __restrict__ emb, const float* __restrict__ Xout,
                          const float* __restrict__ Ws, const float* __restrict__ bsp,
                          float* __restrict__ EL) {
  int tn = blockIdx.x;
  int n = tn & 63;
  int t = threadIdx.x, h = t >> 5, l = t & 31;
  const float* er = emb + (size_t)tn * CE;
  const float* xr = Xout + ((size_t)(n * CHP) + h) * CE;
  float pd = 0.f, px = 0.f, pe = 0.f, ps = 0.f;
  #pragma unroll
  for (int i = 0; i < 8; ++i) {
    int e = l * 8 + i;
    float ev = er[e], xv2 = xr[e];
    pd += ev * xv2; px += xv2 * xv2; pe += ev * ev; ps += fmaxf(ev, 0.f) * Ws[e];
  }
  #pragma unroll
  for (int off = 16; off > 0; off >>= 1) {
    pd += __shfl_down(pd, off, 32);
    px += __shfl_down(px, off, 32);
    pe += __shfl_down(pe, off, 32);
    ps += __shfl_down(ps, off, 32);
  }
  __shared__ float sdot[8], snx[8];
  __shared__ float sne, ssh;
  if (l == 0) {
    sdot[h] = pd;
    snx[h] = sqrtf(px);
    if (h == 0) { sne = sqrtf(pe); ssh = ps + bsp[0]; }
  }
  __syncthreads();
  if (t == 0) {
    const float eps = 1e-8f;
    float y[8];
    float m = -1e30f;
    #pragma unroll
    for (int hh = 0; hh < 8; ++hh) {
      float cs = sdot[hh] / ((sne + eps) * (snx[hh] + eps));
      y[hh] = ssh * cs;
      m = fmaxf(m, y[hh]);
    }
    float sum = 0.f;
    #pragma unroll
    for (int hh = 0; hh < 8; ++hh) sum += expf(y[hh] - m);
    float lse = logf(sum);
    float el = 0.f;
    #pragma unroll
    for (int hh = 0; hh < 8; ++hh) {
      float lp = y[hh] - m - lse;
      el += expf(lp) * lp;
    }
    EL[tn] = el;
  }
}

// ---------------------------------------------------------------------------
extern "C" void kernel_launch(void* const* d_in, const int* in_sizes, int n_in,
                              void* d_out, int out_size, void* d_ws, size_t ws_size,
                              hipStream_t stream) {
  (void)in_sizes; (void)n_in; (void)out_size; (void)ws_size;
  const int*   obs    = (const int*)d_in[0];
  const int*   P      = (const int*)d_in[1];
  const float* embed1 = (const float*)d_in[2];
  const float* Wih    = (const float*)d_in[3];
  // d_in[4] = Whh: provably unused (h0 = 0 and only Hs[0] is consumed)
  const float* bih    = (const float*)d_in[5];
  const float* bhh    = (const float*)d_in[6];
  const float* We2    = (const float*)d_in[7];
  const float* be2    = (const float*)d_in[8];
  const float* Ws     = (const float*)d_in[9];
  const float* bs     = (const float*)d_in[10];
  const float* Wc     = (const float*)d_in[11];
  const float* bc     = (const float*)d_in[12];
  const float* Wm1    = (const float*)d_in[13];
  const float* bm1    = (const float*)d_in[14];
  const float* Wm2    = (const float*)d_in[15];
  const float* bm2    = (const float*)d_in[16];
  const float* eo     = (const float*)d_in[17];
  float* out = (float*)d_out;
  char*  ws  = (char*)d_ws;

  float* emb    = (float*)(ws + B_EMB);
  float* h1     = (float*)(ws + B_H1);
  float* part_db= (float*)(ws + B_PART3);
  int*   flg    = (int*)(ws + B_FLG);
  int*   cnttl  = (int*)(ws + B_CNTTL);
  int*   listtl = (int*)(ws + B_LISTTL);
  float* we2t   = (float*)(ws + B_WE2T);
  float* wm1t   = (float*)(ws + B_WM1T);
  float* xstl   = (float*)(ws + B_XSTL);
  float* parttl = (float*)(ws + B_PARTTL);
  float* wm2t   = (float*)(ws + B_WM2T);
  float* wpm    = (float*)(ws + B_WPM);

  dim3 thr(256);
  init_kernel<<<dim3(514), thr, 0, stream>>>(out, flg, cnttl);
  emb_kernel<<<dim3(256), thr, 0, stream>>>(obs, embed1, emb);
  h1_kernel<<<dim3(256), thr, 0, stream>>>(emb, Wih, bih, bhh, h1);
  trans_kernel<<<dim3(16, 4), thr, 0, stream>>>(We2, we2t, CE, CHID);        // We2T
  x0_kernel<<<dim3(4, 64), thr, 0, stream>>>(h1, we2t, be2, out + O_X);
  trans_kernel<<<dim3(128, 16), thr, 0, stream>>>(Wm1, wm1t, CHID, CA * CE); // Wm1T
  wpm_kernel<<<dim3(256, 4), thr, 0, stream>>>(wm1t, eo, wpm);
  trans_kernel<<<dim3(16, 4), thr, 0, stream>>>(Wm2, wm2t, CE, CHID);        // Wm2T
  tllists_kernel<<<dim3(8), thr, 0, stream>>>(P, cnttl, listtl);
  xstl_kernel<<<dim3(4096), thr, 0, stream>>>(emb, xstl);
  // time-loop model: merged l1+l2 -> parttl, then loss
  tl_kernel<<<dim3(32, 8, 8), thr, 0, stream>>>(wpm, xstl, bm1, wm2t,
                                                cnttl, listtl, 256, parttl);
  ml_kernel<<<dim3(2048), thr, 0, stream>>>(parttl, bm2, emb, out + O_ML);
  // planning loop: 64 chains x 8 eighth-blocks, speculative compacted W
  // stream, lgkm-only barriers, per-step part slots, unconditional flags
  plan2_kernel<<<dim3(512), dim3(512), 0, stream>>>(
      wpm, wm2t, bm1, P, Ws, bs, Wc, bc, bm2,
      out + O_X, out + O_SL, out + O_VAL, out + O_PA, flg, part_db);
  el_kernel<<<dim3(2048), thr, 0, stream>>>(emb, out + O_X, Ws, bs, out + O_EL);
}

// Round 16
// 545.632 us; speedup vs baseline: 1.1638x; 1.1638x over previous
//
#include <hip/hip_runtime.h>

// ---------------------------------------------------------------------------
// Problem constants
// ---------------------------------------------------------------------------
constexpr int CT = 32;      // T
constexpr int CN = 64;      // N
constexpr int CE = 256;     // E = DOBS*V
constexpr int CHID = 1024;
constexpr int CA = 32;      // num options
constexpr int CS = 32;      // planning steps
constexpr int CHP = 8;      // planning horizon
constexpr int TN = CT * CN; // 2048

// d_out float offsets (return order: search_logits, planned_actions, X, value,
// model_loss, embed_loss)
constexpr size_t O_SL  = 0;        // 32*64*32 = 65536
constexpr size_t O_PA  = 65536;    // 64*8     = 512
constexpr size_t O_X   = 66048;    // 64*8*256 = 131072
constexpr size_t O_VAL = 197120;   // 32*64    = 2048
constexpr size_t O_ML  = 199168;   // 32*64*256= 524288
constexpr size_t O_EL  = 723456;   // 32*64    = 2048

// ws byte offsets (~100 MB total)
constexpr size_t B_EMB    = 0;                           // 2 MB   [2048][256] f32
constexpr size_t B_H1     = 2u * 1024 * 1024;            // 256 KB [64][1024]
// control block at 3.5 MB (nothing else lives in 3.5..4 MB)
constexpr size_t B_FLG    = 3584u * 1024;                // 64*8*16 ints = 32 KB
constexpr size_t B_CNTTL  = B_FLG + 64 * 1024;           // 32 ints
constexpr size_t B_LISTTL = B_CNTTL + 4 * 1024;          // 32 KB [32][256]
// 32MB+ multi-phase region: We2T (early) -> Wm1T (mid) -> xstl/parttl/Wm2T
constexpr size_t B_R32    = 4u * 1024 * 1024;
constexpr size_t B_WE2T   = B_R32;                       // 1 MB  (dead after x0)
constexpr size_t B_WM1T   = B_R32;                       // 32 MB (dead after wpm)
constexpr size_t B_XSTL   = B_R32;                       // 4 MB  [2048][512]
constexpr size_t B_PARTTL = B_R32 + 12u * 1024 * 1024;   // 16 MB [2048][8][256]
// plan part buffer: PER-STEP slots (33 x 64 x 8 x 256 f32 = 16.5 MB) at +4MB
// abs, overlapping only xstl/parttl -- dead after ml_kernel (stream-ordered
// before plan2). Slots never reused -> no overwrite race, ever.
constexpr size_t B_PART3  = B_R32;                       // 16.5 MB [33][64][8][256]
constexpr size_t B_WM2T   = B_R32 + 28u * 1024 * 1024;   // 1 MB  [1024][256] (abs +32MB)
constexpr size_t B_WPM    = B_R32 + 32u * 1024 * 1024;   // 64 MB [32][512][1024]

// LDS scalar-state indices
constexpr int SI_FLAG = 0, SI_I = 1, SI_PUSH = 2, SI_IUP = 3;

__device__ __forceinline__ void fma4(float4& a, float s, const float4& w) {
  a.x = fmaf(s, w.x, a.x); a.y = fmaf(s, w.y, a.y);
  a.z = fmaf(s, w.z, a.z); a.w = fmaf(s, w.w, a.w);
}

// LLC-coherent relaxed accessors (cross-block data; no fences needed: producer
// ordering via __syncthreads' vmcnt drain + explicit waitst before flag post)
__device__ __forceinline__ float gld(const float* p) {
  return __hip_atomic_load(p, __ATOMIC_RELAXED, __HIP_MEMORY_SCOPE_AGENT);
}
__device__ __forceinline__ void gst(float* p, float v) {
  __hip_atomic_store(p, v, __ATOMIC_RELAXED, __HIP_MEMORY_SCOPE_AGENT);
}
__device__ __forceinline__ int gldi(const int* p) {
  return __hip_atomic_load(p, __ATOMIC_RELAXED, __HIP_MEMORY_SCOPE_AGENT);
}
__device__ __forceinline__ void gsti(int* p, int v) {
  __hip_atomic_store(p, v, __ATOMIC_RELAXED, __HIP_MEMORY_SCOPE_AGENT);
}
__device__ __forceinline__ void waitst() {
  asm volatile("s_waitcnt vmcnt(0)" ::: "memory");
}
// LDS-only barrier: drains lgkmcnt (LDS ops) but leaves global loads in
// flight across the barrier (unlike __syncthreads' implicit vmcnt(0) drain).
// sched_barrier(0) pins code motion across the point (guide rule #18).
__device__ __forceinline__ void syncL() {
  asm volatile("s_waitcnt lgkmcnt(0)" ::: "memory");
  __builtin_amdgcn_s_barrier();
  __builtin_amdgcn_sched_barrier(0);
}

// ---------------------------------------------------------------------------
// init: zero PA+X span of d_out, per-chain flags, time-loop counters
// ---------------------------------------------------------------------------
__global__ void init_kernel(float* __restrict__ out, int* __restrict__ flg,
                            int* __restrict__ cnt_tl) {
  int idx = blockIdx.x * 256 + threadIdx.x;
  if (idx < 131584) out[O_PA + idx] = 0.f;  // PA (512) + X (131072) contiguous
  if (idx < CN * 8 * 16) flg[idx] = 0;
  if (idx < CA) cnt_tl[idx] = 0;
}

// ---------------------------------------------------------------------------
// emb[t][n][e] = embed1[obs[t][n][e>>4]][e&15]
// ---------------------------------------------------------------------------
__global__ void emb_kernel(const int* __restrict__ obs, const float* __restrict__ embed1,
                           float* __restrict__ emb) {
  int idx = blockIdx.x * 256 + threadIdx.x;
  int b = idx >> 5, k8 = idx & 31;
  int e0 = k8 * 8;
  int d = e0 >> 4;
  int o = obs[b * 16 + d];
  const float* src = embed1 + o * 16 + (e0 & 15);
  float4 v0 = *(const float4*)src;
  float4 v1 = *(const float4*)(src + 4);
  float* dst = emb + (size_t)b * CE + e0;
  *(float4*)dst = v0;
  *(float4*)(dst + 4) = v1;
}

// ---------------------------------------------------------------------------
// One GRU step with h0 = 0 (only Hs[0] used downstream; Whh provably unused)
// ---------------------------------------------------------------------------
__global__ void h1_kernel(const float* __restrict__ emb, const float* __restrict__ Wih,
                          const float* __restrict__ bih, const float* __restrict__ bhh,
                          float* __restrict__ h1) {
  int t = threadIdx.x, bid = blockIdx.x;   // 256 blocks of (64n x 4j)
  int n = t & 63, j = bid * 4 + (t >> 6);
  const float* x = emb + (size_t)n * CE;   // emb[0] rows
  const float* wr = Wih + (size_t)j * CE;
  const float* wz = Wih + (size_t)(CHID + j) * CE;
  const float* wn = Wih + (size_t)(2 * CHID + j) * CE;
  float ar = 0.f, az = 0.f, an = 0.f;
  #pragma unroll 4
  for (int e = 0; e < CE; ++e) {
    float xe = x[e];
    ar += xe * wr[e]; az += xe * wz[e]; an += xe * wn[e];
  }
  ar += bih[j] + bhh[j];
  az += bih[CHID + j] + bhh[CHID + j];
  float r = 1.f / (1.f + expf(-ar));
  float z = 1.f / (1.f + expf(-az));
  float nn = tanhf(an + bih[2 * CHID + j] + r * bhh[2 * CHID + j]);
  h1[(size_t)n * CHID + j] = (1.f - z) * nn;
}

// ---------------------------------------------------------------------------
// Generic 64x64 tiled transpose: in[R][C] -> out[C][R]
// ---------------------------------------------------------------------------
__global__ void trans_kernel(const float* __restrict__ in, float* __restrict__ out,
                             int R, int C) {
  __shared__ float tile[64][65];
  int tj = threadIdx.x & 63, tg = threadIdx.x >> 6;
  int cb = blockIdx.x * 64, rb = blockIdx.y * 64;
  #pragma unroll
  for (int i = 0; i < 16; ++i) {
    int r = tg * 16 + i;
    tile[r][tj] = in[(size_t)(rb + r) * C + cb + tj];
  }
  __syncthreads();
  #pragma unroll
  for (int i = 0; i < 16; ++i) {
    int c2 = tg * 16 + i;
    out[(size_t)(cb + c2) * R + rb + tj] = tile[tj][c2];
  }
}

// ---------------------------------------------------------------------------
// X[:,0] = h1 @ We2^T + be2   (We2T layout [k][e])
// ---------------------------------------------------------------------------
__global__ void x0_kernel(const float* __restrict__ h1, const float* __restrict__ We2T,
                          const float* __restrict__ be2, float* __restrict__ Xout) {
  int et = blockIdx.x, n = blockIdx.y, t = threadIdx.x;
  int el = t & 63, kq = t >> 6;
  __shared__ float hr[1024];
  __shared__ float sred2[4][64];
  for (int idx = t; idx < 1024; idx += 256) hr[idx] = h1[(size_t)n * CHID + idx];
  __syncthreads();
  int e = et * 64 + el;
  float acc = 0.f;
  for (int k = kq * 256; k < kq * 256 + 256; ++k) acc += hr[k] * We2T[(size_t)k * CE + e];
  sred2[kq][el] = acc;
  __syncthreads();
  if (t < 64) {
    float s2 = sred2[0][t] + sred2[1][t] + sred2[2][t] + sred2[3][t] + be2[et * 64 + t];
    Xout[(size_t)(n * CHP) * CE + et * 64 + t] = s2;
  }
}

// ---------------------------------------------------------------------------
// Factorized model weights:
// Wpm[o][e][j]     = sum_a relu( embed_opt[o][a]) * Wm1[j][a*256+e]
// Wpm[o][256+e][j] = sum_a relu(-embed_opt[o][a]) * Wm1[j][a*256+e]
// ---------------------------------------------------------------------------
__global__ void wpm_kernel(const float* __restrict__ Wm1T, const float* __restrict__ eo,
                           float* __restrict__ Wpm) {
  int e = blockIdx.x, jt = blockIdx.y, t = threadIdx.x;
  int j = jt * 256 + t;
  __shared__ float rp[CA * CA], rm[CA * CA];
  for (int idx = t; idx < CA * CA; idx += 256) {
    float v = eo[idx];
    rp[idx] = fmaxf(v, 0.f);
    rm[idx] = fmaxf(-v, 0.f);
  }
  __syncthreads();
  float w[32];
  #pragma unroll
  for (int a = 0; a < 32; ++a) w[a] = Wm1T[(size_t)(a * 256 + e) * CHID + j];
  for (int o = 0; o < 32; ++o) {
    float sp = 0.f, sm = 0.f;
    #pragma unroll
    for (int a = 0; a < 32; ++a) {
      float wa = w[a];
      sp += rp[o * 32 + a] * wa;
      sm += rm[o * 32 + a] * wa;
    }
    Wpm[((size_t)o * 512 + e) * CHID + j] = sp;
    Wpm[((size_t)o * 512 + 256 + e) * CHID + j] = sm;
  }
}

// ---------------------------------------------------------------------------
// Group time-loop rows by option (list order nondeterministic; results aren't)
// ---------------------------------------------------------------------------
__global__ void tllists_kernel(const int* __restrict__ P, int* __restrict__ cnt_tl,
                               int* __restrict__ list_tl) {
  int b = blockIdx.x * 256 + threadIdx.x;
  if (b >= TN) return;
  int a = P[b];
  int slot = atomicAdd(&cnt_tl[a], 1);
  list_tl[a * 256 + slot] = b;
}

// xs_tl[b][k] = relu(+/- prev[b][k&255]),  prev = emb shifted by one t (wrap)
__global__ void xstl_kernel(const float* __restrict__ emb, float* __restrict__ xs) {
  int idx = blockIdx.x * 256 + threadIdx.x;   // < 2048*512
  int b = idx >> 9, k = idx & 511;
  int e = k & 255;
  int bp = (b < CN) ? (b + (CT - 1) * CN) : (b - CN);
  float v = emb[(size_t)bp * CE + e];
  xs[idx] = (k < 256) ? fmaxf(v, 0.f) : fmaxf(-v, 0.f);
}

// ---------------------------------------------------------------------------
// Time-loop model, l1+l2 MERGED: h eighth stays in LDS, l2 eighth ->
// part[row][jt][e] directly. grid (32 o, 8 jt, 8 z), 256 thr.
// ---------------------------------------------------------------------------
__global__ __launch_bounds__(256) void tl_kernel(
    const float* __restrict__ Wpm, const float* __restrict__ xs,
    const float* __restrict__ bm1, const float* __restrict__ Wm2T,
    const int* __restrict__ cnt, const int* __restrict__ list,
    int listStride, float* __restrict__ part) {
  int o = blockIdx.x, jt = blockIdx.y;
  int c = cnt[o];
  if (c <= 0) return;
  __shared__ __align__(16) float sbuf[8192];
  __shared__ __align__(16) float hh[8 * 128];
  __shared__ int srows[8];
  int t = threadIdx.x;
  int jl = t & 31, kq = t >> 5;
  int jb = jt * 128;
  const float* wb = Wpm + (size_t)o * (512 * CHID) + jb + jl * 4;
  for (int g = blockIdx.z; g * 8 < c; g += gridDim.z) {
    int base = g * 8;
    int nr = min(8, c - base);
    if (t < 8) srows[t] = (t < nr) ? list[o * listStride + base + t] : -1;
    __syncthreads();
    for (int idx = t; idx < 4096; idx += 256) {
      int row = srows[idx >> 9];
      sbuf[idx] = (row >= 0) ? xs[(size_t)row * 512 + (idx & 511)] : 0.f;
    }
    __syncthreads();
    float4 acc[8];
    #pragma unroll
    for (int r = 0; r < 8; ++r) acc[r] = make_float4(0.f, 0.f, 0.f, 0.f);
    int kbase = kq * 64;
    for (int k4 = 0; k4 < 64; k4 += 4) {
      int k = kbase + k4;
      float4 w0 = *(const float4*)(wb + (size_t)(k + 0) * CHID);
      float4 w1 = *(const float4*)(wb + (size_t)(k + 1) * CHID);
      float4 w2 = *(const float4*)(wb + (size_t)(k + 2) * CHID);
      float4 w3 = *(const float4*)(wb + (size_t)(k + 3) * CHID);
      #pragma unroll
      for (int r = 0; r < 8; ++r) {
        float4 xv = *(const float4*)&sbuf[r * 512 + k];
        fma4(acc[r], xv.x, w0); fma4(acc[r], xv.y, w1);
        fma4(acc[r], xv.z, w2); fma4(acc[r], xv.w, w3);
      }
    }
    __syncthreads();
    #pragma unroll
    for (int r = 0; r < 8; ++r)
      *(float4*)&sbuf[(kq * 8 + r) * 128 + jl * 4] = acc[r];
    __syncthreads();
    for (int idx = t; idx < 1024; idx += 256) {
      int r = idx >> 7, jc = idx & 127;
      float ssum = 0.f;
      #pragma unroll
      for (int q8 = 0; q8 < 8; ++q8) ssum += sbuf[(q8 * 8 + r) * 128 + jc];
      hh[r * 128 + jc] = fmaxf(ssum + bm1[jb + jc], 0.f);
    }
    __syncthreads();
    // l2 eighth: thread t = e; part[row][jt][e] = sum_j hh[r][j]*Wm2T[jb+j][e]
    float acc2[8];
    #pragma unroll
    for (int r = 0; r < 8; ++r) acc2[r] = 0.f;
    for (int jj = 0; jj < 128; jj += 4) {
      float w0 = Wm2T[(size_t)(jb + jj + 0) * CE + t];
      float w1 = Wm2T[(size_t)(jb + jj + 1) * CE + t];
      float w2 = Wm2T[(size_t)(jb + jj + 2) * CE + t];
      float w3 = Wm2T[(size_t)(jb + jj + 3) * CE + t];
      #pragma unroll
      for (int r = 0; r < 8; ++r) {
        float4 hv = *(const float4*)&hh[r * 128 + jj];
        acc2[r] += hv.x * w0 + hv.y * w1 + hv.z * w2 + hv.w * w3;
      }
    }
    #pragma unroll
    for (int r = 0; r < 8; ++r)
      if (srows[r] >= 0)
        part[((size_t)srows[r] * 8 + jt) * CE + t] = acc2[r];
    __syncthreads();
  }
}

// model_loss = (sum(partials)+bm2 - emb)^2
__global__ void ml_kernel(const float* __restrict__ part, const float* __restrict__ bm2,
                          const float* __restrict__ emb, float* __restrict__ ML) {
  int idx = blockIdx.x * 256 + threadIdx.x;   // < 2048*256
  int b = idx >> 8, e = idx & 255;
  float outv = bm2[e];
  #pragma unroll
  for (int q = 0; q < 8; ++q) outv += part[((size_t)b * 8 + q) * CE + e];
  float d = outv - emb[idx];
  ML[idx] = d * d;
}

// ---------------------------------------------------------------------------
// plan2: 512 blocks = 64 independent chains x 8 j-eighth blocks, 512 thr.
// Round-16: conditional WAIT / unconditional POST.
//  - POST: every replica posts flg=s+1 every step (cheap, hang-proof).
//  - WAIT: only needed when this chain PUSHED at s-1 (the only cross-block
//    data read). Pops skip the LLC spin entirely -> serial floor cut.
//  - W gather back INSIDE the push branch (round-15 speculation doubled
//    FETCH and time tracked traffic: strictly negative).
// Per-step part slots (no reuse -> no race); syncL for LDS-only barriers.
// ---------------------------------------------------------------------------
__global__ __launch_bounds__(512) void plan2_kernel(
    const float* __restrict__ Wpm, const float* __restrict__ Wm2T,
    const float* __restrict__ bm1g, const int* __restrict__ P,
    const float* __restrict__ Wsg, const float* __restrict__ bsg,
    const float* __restrict__ Wcg, const float* __restrict__ bcg,
    const float* __restrict__ bm2, float* __restrict__ Xout,
    float* __restrict__ SLout, float* __restrict__ VALout,
    float* __restrict__ PAout, int* __restrict__ flg,
    float* __restrict__ part_db) {
  __shared__ float Xlds[CHP * CE];      // replicated plan buffer (8 KB)
  __shared__ float sh[128];             // h eighth
  __shared__ __align__(16) float red[2048];  // 16-way partials / l2 halves
  __shared__ float sx[256];
  __shared__ float sred[8];
  __shared__ float svals[32];
  __shared__ int   sint[4];
  __shared__ float logits_s[32];

  int bid = blockIdx.x, t = threadIdx.x;
  int n = bid >> 3, q = bid & 7;
  int jb = q * 128;
  int c2 = t >> 3, g = t & 7;
  int jq = t & 31, kg = t >> 5;         // l1: jq = float4 j-lane, kg = row-group
  int e2 = t & 255, hf = t >> 8;        // l2: e lane, kl half

  // prologue: replicated chain state
  for (int idx = t; idx < CHP * CE; idx += 512)
    Xlds[idx] = Xout[(size_t)n * (CHP * CE) + idx];
  if (t < 32) logits_s[t] = 0.f;
  if (t < 4) sint[t] = 0;
  __syncthreads();

  for (int s = 0; s <= CS; ++s) {
    // read-only prefetch (L2-warm; hidden under the flag wait when pushing)
    float wsv = 0.f, bm2v = 0.f, bcv = 0.f, bsv = bsg[0];
    float wcv[32];
    if (t < 256) {
      wsv = Wsg[t]; bm2v = bm2[t];
      #pragma unroll
      for (int i = 0; i < 32; ++i) wcv[i] = Wcg[c2 * CE + g * 32 + i];
    }
    if (t < CA) bcv = bcg[t];

    // ---- epilogue of step s-1: WAIT only if pushed (posts unconditional) --
    if (s > 0) {
      if (sint[SI_PUSH]) {
        #pragma unroll
        for (int f = 0; f < 8; ++f) {
          const int* fp = &flg[(n * 8 + f) * 16];
          while (gldi(fp) < s) __builtin_amdgcn_s_sleep(1);
        }
        int Iup = sint[SI_IUP];
        if (t < 256) {
          float outv = bm2v;
          #pragma unroll
          for (int qq = 0; qq < 8; ++qq)
            outv += gld(&part_db[(((size_t)(s - 1) * CN + n) * 8 + qq) * CE + t]);
          Xlds[Iup * CE + t] = outv;
          if (q == 0) Xout[((size_t)(n * CHP) + Iup) * CE + t] = outv;
          sx[t] = outv;
        }
        if (t == 0) sint[SI_I] = Iup;
      } else {
        int I0 = sint[SI_I];
        int Inew = (I0 - 1 > 0) ? I0 - 1 : 0;
        if (t < 256) sx[t] = Xlds[Inew * CE + t];
        if (t == 0) sint[SI_I] = Inew;
      }
      if (s == CS) break;  // final epilogue only (uniform)
    } else {
      if (t < 256) sx[t] = Xlds[t];
      if (t == 0) sint[SI_I] = 0;
    }
    syncL();               // sx/sint visible (LDS only)
    int I = sint[SI_I];
    int a = P[s * CN + n];

    // ---- decision segment A ----
    if (t < 256) {
      float v = fmaxf(sx[t], 0.f) * wsv;
      #pragma unroll
      for (int off = 32; off > 0; off >>= 1) v += __shfl_down(v, off, 64);
      if ((t & 63) == 0) sred[t >> 6] = v;
      float pv = 0.f;
      #pragma unroll 4
      for (int i = 0; i < 32; ++i)
        pv += fmaxf(sx[g * 32 + i], 0.f) * wcv[i];
      pv += __shfl_down(pv, 4, 8);
      pv += __shfl_down(pv, 2, 8);
      pv += __shfl_down(pv, 1, 8);
      if (g == 0) svals[c2] = pv + bcv;
    }
    syncL();
    // ---- decision segment B (wave 0 only; is_new via ballot) ----
    if (t < CA) {
      float sharp = sred[0] + sred[1] + sred[2] + sred[3] + bsv;
      bool nz = (logits_s[t] != 0.f);
      unsigned long long bal = __ballot(nz);
      float v = svals[t];
      float slv = (bal == 0ull) ? sharp * v : logits_s[t];
      if (q == 0) SLout[(size_t)(s * CN + n) * CA + t] = slv;
      logits_s[t] = slv - (t == a ? 1e8f : 0.f);
      if (t == a) {
        if (q == 0) { VALout[s * CN + n] = slv; PAout[n * CHP + I] = (float)a; }
        sint[SI_PUSH] = (v > 0.f) ? 1 : 0;
        sint[SI_IUP] = (I + 1 < CHP - 1) ? I + 1 : CHP - 1;
      }
    }
    syncL();

    // ---- model eval (push only): compacted 256-row W gather ----
    if (sint[SI_PUSH]) {
      const float* wbase = Wpm + (size_t)a * (512 * CHID) + jb + jq * 4;
      float4 acc; acc.x = acc.y = acc.z = acc.w = 0.f;
      #pragma unroll 8
      for (int ii = 0; ii < 16; ++ii) {
        int e = kg * 16 + ii;
        float xv = sx[e];
        int row = (xv > 0.f) ? e : 256 + e;
        float4 wv = *(const float4*)(wbase + (size_t)row * CHID);
        fma4(acc, fabsf(xv), wv);
      }
      *(float4*)&red[kg * 128 + jq * 4] = acc;
      syncL();
      if (t < 128) {
        float s1 = 0.f;
        #pragma unroll
        for (int gg = 0; gg < 16; ++gg) s1 += red[gg * 128 + t];
        sh[t] = fmaxf(s1 + bm1g[jb + t], 0.f);
      }
      syncL();
      // l2: part_q[e] = sum_{kl<128} sh[kl] * Wm2T[(jb+kl)*CE+e], 2x64 split
      {
        const float* w2 = Wm2T + (size_t)(jb + hf * 64) * CE + e2;
        float a2 = 0.f;
        #pragma unroll 8
        for (int kl = 0; kl < 64; ++kl)
          a2 = fmaf(sh[hf * 64 + kl], w2[(size_t)kl * CE], a2);
        red[hf * 256 + e2] = a2;
      }
      syncL();
      if (t < 256) {
        gst(&part_db[(((size_t)s * CN + n) * 8 + q) * CE + t],
            red[t] + red[256 + t]);
      }
    }
    __syncthreads();              // full drain: all threads' part stores done
    if (t == 0) {
      waitst();
      gsti(&flg[(n * 8 + q) * 16], s + 1);   // UNCONDITIONAL post
    }
    __syncthreads();
  }
}

// ---------------------------------------------------------------------------
// embed_loss
// ---------------------------------------------------------------------------
__global__ void el_kernel(const float* __restrict__ emb, const float* __restrict__ Xout,
                          const float* __restrict__ Ws, const float* __restrict__ bsp,
                          float* __restrict__ EL) {
  int tn = blockIdx.x;
  int n = tn & 63;
  int t = threadIdx.x, h = t >> 5, l = t & 31;
  const float* er = emb + (size_t)tn * CE;
  const float* xr = Xout + ((size_t)(n * CHP) + h) * CE;
  float pd = 0.f, px = 0.f, pe = 0.f, ps = 0.f;
  #pragma unroll
  for (int i = 0; i < 8; ++i) {
    int e = l * 8 + i;
    float ev = er[e], xv2 = xr[e];
    pd += ev * xv2; px += xv2 * xv2; pe += ev * ev; ps += fmaxf(ev, 0.f) * Ws[e];
  }
  #pragma unroll
  for (int off = 16; off > 0; off >>= 1) {
    pd += __shfl_down(pd, off, 32);
    px += __shfl_down(px, off, 32);
    pe += __shfl_down(pe, off, 32);
    ps += __shfl_down(ps, off, 32);
  }
  __shared__ float sdot[8], snx[8];
  __shared__ float sne, ssh;
  if (l == 0) {
    sdot[h] = pd;
    snx[h] = sqrtf(px);
    if (h == 0) { sne = sqrtf(pe); ssh = ps + bsp[0]; }
  }
  __syncthreads();
  if (t == 0) {
    const float eps = 1e-8f;
    float y[8];
    float m = -1e30f;
    #pragma unroll
    for (int hh = 0; hh < 8; ++hh) {
      float cs = sdot[hh] / ((sne + eps) * (snx[hh] + eps));
      y[hh] = ssh * cs;
      m = fmaxf(m, y[hh]);
    }
    float sum = 0.f;
    #pragma unroll
    for (int hh = 0; hh < 8; ++hh) sum += expf(y[hh] - m);
    float lse = logf(sum);
    float el = 0.f;
    #pragma unroll
    for (int hh = 0; hh < 8; ++hh) {
      float lp = y[hh] - m - lse;
      el += expf(lp) * lp;
    }
    EL[tn] = el;
  }
}

// ---------------------------------------------------------------------------
extern "C" void kernel_launch(void* const* d_in, const int* in_sizes, int n_in,
                              void* d_out, int out_size, void* d_ws, size_t ws_size,
                              hipStream_t stream) {
  (void)in_sizes; (void)n_in; (void)out_size; (void)ws_size;
  const int*   obs    = (const int*)d_in[0];
  const int*   P      = (const int*)d_in[1];
  const float* embed1 = (const float*)d_in[2];
  const float* Wih    = (const float*)d_in[3];
  // d_in[4] = Whh: provably unused (h0 = 0 and only Hs[0] is consumed)
  const float* bih    = (const float*)d_in[5];
  const float* bhh    = (const float*)d_in[6];
  const float* We2    = (const float*)d_in[7];
  const float* be2    = (const float*)d_in[8];
  const float* Ws     = (const float*)d_in[9];
  const float* bs     = (const float*)d_in[10];
  const float* Wc     = (const float*)d_in[11];
  const float* bc     = (const float*)d_in[12];
  const float* Wm1    = (const float*)d_in[13];
  const float* bm1    = (const float*)d_in[14];
  const float* Wm2    = (const float*)d_in[15];
  const float* bm2    = (const float*)d_in[16];
  const float* eo     = (const float*)d_in[17];
  float* out = (float*)d_out;
  char*  ws  = (char*)d_ws;

  float* emb    = (float*)(ws + B_EMB);
  float* h1     = (float*)(ws + B_H1);
  float* part_db= (float*)(ws + B_PART3);
  int*   flg    = (int*)(ws + B_FLG);
  int*   cnttl  = (int*)(ws + B_CNTTL);
  int*   listtl = (int*)(ws + B_LISTTL);
  float* we2t   = (float*)(ws + B_WE2T);
  float* wm1t   = (float*)(ws + B_WM1T);
  float* xstl   = (float*)(ws + B_XSTL);
  float* parttl = (float*)(ws + B_PARTTL);
  float* wm2t   = (float*)(ws + B_WM2T);
  float* wpm    = (float*)(ws + B_WPM);

  dim3 thr(256);
  init_kernel<<<dim3(514), thr, 0, stream>>>(out, flg, cnttl);
  emb_kernel<<<dim3(256), thr, 0, stream>>>(obs, embed1, emb);
  h1_kernel<<<dim3(256), thr, 0, stream>>>(emb, Wih, bih, bhh, h1);
  trans_kernel<<<dim3(16, 4), thr, 0, stream>>>(We2, we2t, CE, CHID);        // We2T
  x0_kernel<<<dim3(4, 64), thr, 0, stream>>>(h1, we2t, be2, out + O_X);
  trans_kernel<<<dim3(128, 16), thr, 0, stream>>>(Wm1, wm1t, CHID, CA * CE); // Wm1T
  wpm_kernel<<<dim3(256, 4), thr, 0, stream>>>(wm1t, eo, wpm);
  trans_kernel<<<dim3(16, 4), thr, 0, stream>>>(Wm2, wm2t, CE, CHID);        // Wm2T
  tllists_kernel<<<dim3(8), thr, 0, stream>>>(P, cnttl, listtl);
  xstl_kernel<<<dim3(4096), thr, 0, stream>>>(emb, xstl);
  // time-loop model: merged l1+l2 -> parttl, then loss
  tl_kernel<<<dim3(32, 8, 8), thr, 0, stream>>>(wpm, xstl, bm1, wm2t,
                                                cnttl, listtl, 256, parttl);
  ml_kernel<<<dim3(2048), thr, 0, stream>>>(parttl, bm2, emb, out + O_ML);
  // planning loop: 64 chains x 8 eighth-blocks, compacted W stream,
  // conditional wait / unconditional post, per-step part slots
  plan2_kernel<<<dim3(512), dim3(512), 0, stream>>>(
      wpm, wm2t, bm1, P, Ws, bs, Wc, bc, bm2,
      out + O_X, out + O_SL, out + O_VAL, out + O_PA, flg, part_db);
  el_kernel<<<dim3(2048), thr, 0, stream>>>(emb, out + O_X, Ws, bs, out + O_EL);
}